// Round 8
// baseline (67.882 us; speedup 1.0000x reference)
//
#include <hip/hip_runtime.h>
#include <hip/hip_cooperative_groups.h>

namespace cg = cooperative_groups;

// Inclusive prefix-sum along L of X[B=8][L=4096][D=64][N=16] fp32.
// Single-pass cooperative kernel: tile scanned into regs+LDS, grid.sync(),
// gather chunk offsets from csum (L2-resident), add, write. One x read.

typedef float f4 __attribute__((ext_vector_type(4)));

constexpr int BB = 8;
constexpr int LL = 4096;
constexpr int DN = 1024;        // D*N, contiguous per (b,l)
constexpr int C  = 128;         // chunks per batch column
constexpr int S  = LL / C;      // 32 rows per chunk
constexpr int NBLK = BB * C;    // 1024 blocks
constexpr int TPB = 256;        // thread owns one float4 column group
constexpr int RREG = 23;        // rows of the tile kept in registers (92 VGPR)
constexpr int RLDS = S - RREG;  // 9 rows kept in LDS (36 KB/block)

__global__ __launch_bounds__(TPB, 4) void scan_coop(
    const float* __restrict__ x, float* __restrict__ out,
    float* __restrict__ csum) {
    __shared__ f4 lds[RLDS][TPB];
    const int bid = blockIdx.x;
    const int b = bid >> 7, c = bid & (C - 1);
    const int t = threadIdx.x;
    const size_t base = (size_t)b * LL * DN + (size_t)c * S * DN;
    const f4* xp = reinterpret_cast<const f4*>(x + base) + t;

    // Phase 1: in-register inclusive scan of this tile's column.
    f4 run = (f4)0.f;
    f4 v[RREG];
    #pragma unroll
    for (int i = 0; i < RREG; ++i) { run += xp[i * (DN / 4)]; v[i] = run; }
    #pragma unroll
    for (int i = 0; i < RLDS; ++i) { run += xp[(RREG + i) * (DN / 4)]; lds[i][t] = run; }

    // Publish tile aggregate (inclusive value of last row).
    reinterpret_cast<f4*>(csum + (size_t)bid * DN)[t] = run;

    cg::this_grid().sync();

    // Phase 2: exclusive offset = sum of preceding chunks' aggregates.
    // c independent loads from the 4 MB csum (L2-resident), fully pipelined.
    f4 off = (f4)0.f;
    const f4* cs = reinterpret_cast<const f4*>(csum + (size_t)(b * C) * DN) + t;
    #pragma unroll 4
    for (int j = 0; j < c; ++j) off += cs[j * (DN / 4)];

    f4* op = reinterpret_cast<f4*>(out + base) + t;
    #pragma unroll
    for (int i = 0; i < RREG; ++i) op[i * (DN / 4)] = v[i] + off;
    #pragma unroll
    for (int i = 0; i < RLDS; ++i) op[(RREG + i) * (DN / 4)] = lds[i][t] + off;
}

// ---- Fallback: proven 2-pass reduce-then-scan (round 7, 67 us) ----
constexpr int C2 = 64, S2 = LL / C2;

__global__ __launch_bounds__(TPB) void k1(const float* __restrict__ x,
                                          float* __restrict__ csum) {
    const int bid = blockIdx.x;
    const int b = bid >> 6, c = bid & (C2 - 1);
    const int t = threadIdx.x;
    const f4* xp = reinterpret_cast<const f4*>(
        x + (size_t)b * LL * DN + (size_t)c * S2 * DN) + t;
    f4 acc = (f4)0.f;
    #pragma unroll 8
    for (int i = 0; i < S2; ++i) acc += xp[i * (DN / 4)];
    reinterpret_cast<f4*>(csum + (size_t)bid * DN)[t] = acc;
}

__global__ __launch_bounds__(TPB) void k2(const float* __restrict__ x,
                                          const float* __restrict__ csum,
                                          float* __restrict__ out) {
    const int bid = blockIdx.x;
    const int b = bid >> 6, c = bid & (C2 - 1);
    const int t = threadIdx.x;
    f4 run = (f4)0.f;
    const f4* cs = reinterpret_cast<const f4*>(csum + (size_t)(b * C2) * DN) + t;
    #pragma unroll 4
    for (int j = 0; j < c; ++j) run += cs[j * (DN / 4)];
    const size_t base = (size_t)b * LL * DN + (size_t)c * S2 * DN;
    const f4* xp = reinterpret_cast<const f4*>(x + base) + t;
    f4* op = reinterpret_cast<f4*>(out + base) + t;
    #pragma unroll 4
    for (int i = 0; i < S2; ++i) {
        run += xp[i * (DN / 4)];
        __builtin_nontemporal_store(run, op + i * (DN / 4));
    }
}

extern "C" void kernel_launch(void* const* d_in, const int* in_sizes, int n_in,
                              void* d_out, int out_size, void* d_ws, size_t ws_size,
                              hipStream_t stream) {
    const float* x = (const float*)d_in[0];
    float* out = (float*)d_out;
    float* csum = (float*)d_ws;    // 4 MiB, fully overwritten before use

    int nb = 0;
    hipError_t e = hipOccupancyMaxActiveBlocksPerMultiprocessor(&nb, scan_coop, TPB, 0);
    if (e == hipSuccess && nb * 256 /* CUs on MI355X */ >= NBLK) {
        void* args[] = {(void*)&x, (void*)&out, (void*)&csum};
        (void)hipLaunchCooperativeKernel(scan_coop, dim3(NBLK), dim3(TPB),
                                         args, 0, stream);
    } else {
        k1<<<dim3(BB * C2), dim3(TPB), 0, stream>>>(x, csum);
        k2<<<dim3(BB * C2), dim3(TPB), 0, stream>>>(x, csum, out);
    }
}